// Round 3
// baseline (355.214 us; speedup 1.0000x reference)
//
#include <hip/hip_runtime.h>
#include <math.h>

namespace {

constexpr int Dm = 2048;

__device__ __forceinline__ float dot4(float4 u, float4 v) {
  return u.x * v.x + u.y * v.y + u.z * v.z + u.w * v.w;
}

// F1: xbuf = feats + mod_emb (broadcast); summ = mean_s feats + mod_emb; zero tickets
__global__ __launch_bounds__(256) void k_pre(const float* __restrict__ feats,
                                             const float* __restrict__ mod,
                                             float* __restrict__ xbuf,
                                             float* __restrict__ summ,
                                             int* __restrict__ cnt) {
  int idx = blockIdx.x * 256 + threadIdx.x;   // 131072 total (512 blocks)
  int b = idx >> 11, i = idx & 2047;
  xbuf[idx] = feats[idx] + mod[((b >> 3) << 11) + i];
  if (blockIdx.x < 64) {
    int sidx = idx;                            // 0..16383
    int m = sidx >> 11;
    float s = 0.f;
#pragma unroll
    for (int t = 0; t < 8; ++t) s += feats[((m * 8 + t) << 11) + (sidx & 2047)];
    summ[sidx] = s * 0.125f + mod[sidx];
  }
  if (blockIdx.x == 511 && threadIdx.x < 2) cnt[threadIdx.x] = 0;
}

// F2: blocks 0..511 -> h1 = relu([summ|ctx] @ rW1.T + rb1);  512..1023 -> q0 = x0 @ Wq.T + b
__global__ __launch_bounds__(256) void k_big1(const float* __restrict__ summ,
                                              const float* __restrict__ ctx,
                                              const float* __restrict__ xbuf,
                                              const float* __restrict__ rW1,
                                              const float* __restrict__ rb1,
                                              const float* __restrict__ W_in,
                                              const float* __restrict__ b_in,
                                              float* __restrict__ h1,
                                              float* __restrict__ q0) {
  __shared__ float As[8 * Dm];
  int tid = threadIdx.x, wave = tid >> 6, lane = tid & 63;
  if (blockIdx.x < 512) {
    for (int t = tid; t < 8 * Dm; t += 256) As[t] = summ[t];
    __syncthreads();
    int j = blockIdx.x * 4 + wave;
    const float* Wr = rW1 + (size_t)j * 4096;
    float acc[8] = {0, 0, 0, 0, 0, 0, 0, 0};
    float accC = 0.f;
    for (int i = lane * 4; i < Dm; i += 256) {
      float4 w1 = *(const float4*)(Wr + i);
      float4 w2 = *(const float4*)(Wr + 2048 + i);
      float4 c = *(const float4*)(ctx + i);
      accC += dot4(w2, c);
#pragma unroll
      for (int m = 0; m < 8; ++m) {
        float4 a = *(const float4*)(As + (m << 11) + i);
        acc[m] += dot4(w1, a);
      }
    }
#pragma unroll
    for (int o = 32; o > 0; o >>= 1) {
      accC += __shfl_down(accC, o, 64);
#pragma unroll
      for (int m = 0; m < 8; ++m) acc[m] += __shfl_down(acc[m], o, 64);
    }
    if (lane == 0) {
      float base = accC + rb1[j];
#pragma unroll
      for (int m = 0; m < 8; ++m) h1[(m << 11) + j] = fmaxf(acc[m] + base, 0.f);
    }
  } else {
    for (int t = tid; t < 8 * Dm; t += 256) {
      int m = t >> 11;
      As[t] = xbuf[(size_t)(m * 8) * Dm + (t & 2047)];   // x[m,0,:]
    }
    __syncthreads();
    int j = (blockIdx.x - 512) * 4 + wave;
    const float* Wr = W_in + (size_t)j * Dm;
    float acc[8] = {0, 0, 0, 0, 0, 0, 0, 0};
    for (int i = lane * 4; i < Dm; i += 256) {
      float4 w = *(const float4*)(Wr + i);
#pragma unroll
      for (int m = 0; m < 8; ++m) {
        float4 a = *(const float4*)(As + (m << 11) + i);
        acc[m] += dot4(w, a);
      }
    }
#pragma unroll
    for (int o = 32; o > 0; o >>= 1)
#pragma unroll
      for (int m = 0; m < 8; ++m) acc[m] += __shfl_down(acc[m], o, 64);
    if (lane == 0) {
      float b = b_in[j];
#pragma unroll
      for (int m = 0; m < 8; ++m) q0[(m << 11) + j] = acc[m] + b;
    }
  }
}

// F3: blocks 0..255 -> h2 = relu(h1 @ rW2.T + rb2); 256..383 -> qw (per-head K projection)
__global__ __launch_bounds__(256) void k_big2(const float* __restrict__ h1,
                                              const float* __restrict__ rW2,
                                              const float* __restrict__ rb2,
                                              const float* __restrict__ q0,
                                              const float* __restrict__ W_in,
                                              float* __restrict__ h2,
                                              float* __restrict__ qw) {
  __shared__ float As[8 * Dm];
  int tid = threadIdx.x, wave = tid >> 6, lane = tid & 63;
  if (blockIdx.x < 256) {
    for (int t = tid; t < 8 * Dm; t += 256) As[t] = h1[t];
    __syncthreads();
    int j = blockIdx.x * 4 + wave;     // 0..1023
    const float* Wr = rW2 + (size_t)j * Dm;
    float acc[8] = {0, 0, 0, 0, 0, 0, 0, 0};
    for (int i = lane * 4; i < Dm; i += 256) {
      float4 w = *(const float4*)(Wr + i);
#pragma unroll
      for (int m = 0; m < 8; ++m) {
        float4 a = *(const float4*)(As + (m << 11) + i);
        acc[m] += dot4(w, a);
      }
    }
#pragma unroll
    for (int o = 32; o > 0; o >>= 1)
#pragma unroll
      for (int m = 0; m < 8; ++m) acc[m] += __shfl_down(acc[m], o, 64);
    if (lane == 0) {
      float b = rb2[j];
#pragma unroll
      for (int m = 0; m < 8; ++m) h2[m * 1024 + j] = fmaxf(acc[m] + b, 0.f);
    }
  } else {
    int bb = blockIdx.x - 256;          // 0..127
    int h = bb >> 3, chunk = bb & 7;
    int i0 = chunk * 256 + tid;
    for (int t = tid; t < 1024; t += 256) {
      int m = t >> 7, d = t & 127;
      As[t] = q0[(m << 11) + h * 128 + d];
    }
    __syncthreads();
    float acc[8] = {0, 0, 0, 0, 0, 0, 0, 0};
    const float* Wb = W_in + (size_t)(Dm + h * 128) * Dm + i0;
    for (int d = 0; d < 128; ++d) {
      float w = Wb[(size_t)d * Dm];
#pragma unroll
      for (int m = 0; m < 8; ++m) acc[m] += w * As[(m << 7) + d];
    }
#pragma unroll
    for (int m = 0; m < 8; ++m) qw[(size_t)(m * 16 + h) * Dm + i0] = acc[m];
  }
}

// F4: per-head block: redundant routing head + attention weights + xbar[h]
__global__ __launch_bounds__(256) void k_attn(const float* __restrict__ h2,
                                              const float* __restrict__ rW3,
                                              const float* __restrict__ rb3,
                                              const float* __restrict__ qw,
                                              const float* __restrict__ xbuf,
                                              float* __restrict__ xbar,
                                              float* __restrict__ out_rw) {
  __shared__ float sig[8], wm[64], sv[64], att[64], mask_s[8];
  int tid = threadIdx.x, wave = tid >> 6, lane = tid & 63;
  int h = blockIdx.x;
  // routing head (redundant per block; tiny)
  for (int mi = 0; mi < 2; ++mi) {
    int m = wave + mi * 4;
    float acc = 0.f;
    for (int i = lane * 4; i < 1024; i += 256) {
      float4 w = *(const float4*)(rW3 + i);
      float4 a = *(const float4*)(h2 + m * 1024 + i);
      acc += dot4(w, a);
    }
#pragma unroll
    for (int o = 32; o > 0; o >>= 1) acc += __shfl_down(acc, o, 64);
    if (lane == 0) sig[m] = 1.f / (1.f + expf(-(acc + rb3[0])));
  }
  __syncthreads();
  if (tid < 64) {
    float tot = 0.f;
#pragma unroll
    for (int m = 0; m < 8; ++m) tot += sig[m];
    int r = tid >> 3, c = tid & 7;
    wm[tid] = (sig[r] / tot) * (sig[c] / tot);
    if (h == 0 && tid < 8) out_rw[tid] = sig[tid] / tot;
  }
  __syncthreads();
  if (tid < 64) {
    float v = wm[tid];
    int rank = 0;
    for (int t = 0; t < 64; ++t) {
      float u = wm[t];
      rank += (u < v) || (u == v && t < tid);
    }
    sv[rank] = v;
  }
  __syncthreads();
  if (tid < 8) {
    double pos = 0.9 * 63.0;
    int lo = (int)pos;
    double frac = pos - (double)lo;
    float thr = (float)((double)sv[lo] + frac * ((double)sv[lo + 1] - (double)sv[lo]));
    mask_s[tid] = (wm[tid] < thr) ? -1e9f : 0.f;   // row 0 of wmat
  }
  __syncthreads();
  // attention weights for head h (query position 0 only)
  for (int mi = 0; mi < 2; ++mi) {
    int m = wave + mi * 4;
    const float* qr = qw + (size_t)(m * 16 + h) * Dm;
    float sc[8];
#pragma unroll
    for (int k = 0; k < 8; ++k) {
      const float* xr = xbuf + (size_t)(m * 8 + k) * Dm;
      float acc = 0.f;
      for (int i = lane * 4; i < Dm; i += 256) {
        float4 qv = *(const float4*)(qr + i);
        float4 xv = *(const float4*)(xr + i);
        acc += dot4(qv, xv);
      }
#pragma unroll
      for (int o = 32; o > 0; o >>= 1) acc += __shfl_xor(acc, o, 64);
      sc[k] = acc * 0.08838834764831845f + mask_s[k];
    }
    float mx = sc[0];
#pragma unroll
    for (int k = 1; k < 8; ++k) mx = fmaxf(mx, sc[k]);
    float se = 0.f;
#pragma unroll
    for (int k = 0; k < 8; ++k) { sc[k] = expf(sc[k] - mx); se += sc[k]; }
    float inv = 1.f / se;
    if (lane == 0) {
#pragma unroll
      for (int k = 0; k < 8; ++k) att[m * 8 + k] = sc[k] * inv;
    }
  }
  __syncthreads();
  // xbar[h][i] = (1/8) sum_b att[b] * xbuf[b][i]
  for (int i = tid; i < Dm; i += 256) {
    float acc = 0.f;
#pragma unroll
    for (int b = 0; b < 64; ++b) acc += att[b] * xbuf[(size_t)b * Dm + i];
    xbar[(size_t)h * Dm + i] = acc * 0.125f;
  }
}

// generic 4-row matvec: out[j] = dot(Arow(j/G), W[j]) + b1[j]
__global__ __launch_bounds__(256) void k_matvec(const float* __restrict__ A, int G,
                                                const float* __restrict__ W,
                                                const float* __restrict__ b1,
                                                float* __restrict__ out) {
  __shared__ float As[Dm];
  int j0 = blockIdx.x * 4;
  const float* Arow = A + (size_t)(j0 / G) * Dm;
  for (int t = threadIdx.x; t < Dm; t += 256) As[t] = Arow[t];
  __syncthreads();
  int wave = threadIdx.x >> 6, lane = threadIdx.x & 63;
  int j = j0 + wave;
  const float* Wr = W + (size_t)j * Dm;
  float acc = 0.f;
  for (int i = lane * 4; i < Dm; i += 256) {
    float4 w = *(const float4*)(Wr + i);
    float4 a = *(const float4*)(As + i);
    acc += dot4(w, a);
  }
#pragma unroll
  for (int o = 32; o > 0; o >>= 1) acc += __shfl_down(acc, o, 64);
  if (lane == 0) out[j] = acc + b1[j];
}

// F7: gbuf = relu(attd @ gW1.T + gb1); last block computes gate -> gates, topi
__global__ __launch_bounds__(256) void k_gbuf_gate(const float* __restrict__ attd,
                                                   const float* __restrict__ gW1,
                                                   const float* __restrict__ gb1,
                                                   const float* __restrict__ gW2,
                                                   const float* __restrict__ gb2,
                                                   float* __restrict__ gbuf,
                                                   float* __restrict__ gates,
                                                   int* __restrict__ topi,
                                                   int* __restrict__ cnt) {
  __shared__ float As[Dm];
  __shared__ float logits[8];
  __shared__ int amLast;
  int tid = threadIdx.x, wave = tid >> 6, lane = tid & 63;
  for (int t = tid; t < Dm; t += 256) As[t] = attd[t];
  __syncthreads();
  int j = blockIdx.x * 4 + wave;   // 1024 outputs / 256 blocks
  const float* Wr = gW1 + (size_t)j * Dm;
  float acc = 0.f;
  for (int i = lane * 4; i < Dm; i += 256) {
    float4 w = *(const float4*)(Wr + i);
    float4 a = *(const float4*)(As + i);
    acc += dot4(w, a);
  }
#pragma unroll
  for (int o = 32; o > 0; o >>= 1) acc += __shfl_down(acc, o, 64);
  if (lane == 0) gbuf[j] = fmaxf(acc + gb1[j], 0.f);
  __threadfence();
  __syncthreads();
  if (tid == 0) amLast = (atomicAdd(cnt, 1) == (int)gridDim.x - 1);
  __syncthreads();
  if (!amLast) return;
  __threadfence();
  // gate: 8 logits over gbuf[1024]
  for (int ei = wave; ei < 8; ei += 4) {
    float a2 = 0.f;
    for (int i = lane * 4; i < 1024; i += 256) {
      float4 w = *(const float4*)(gW2 + ei * 1024 + i);
      float4 g = *(const float4*)(gbuf + i);
      a2 += dot4(w, g);
    }
#pragma unroll
    for (int o = 32; o > 0; o >>= 1) a2 += __shfl_down(a2, o, 64);
    if (lane == 0) logits[ei] = a2 + gb2[ei];
  }
  __syncthreads();
  if (tid == 0) {
    float mx = logits[0];
    for (int e = 1; e < 8; ++e) mx = fmaxf(mx, logits[e]);
    float p[8], se = 0.f;
    for (int e = 0; e < 8; ++e) { p[e] = expf(logits[e] - mx); se += p[e]; }
    for (int e = 0; e < 8; ++e) p[e] /= se;
    int used[8] = {0, 0, 0, 0, 0, 0, 0, 0};
    float tv[3]; int ti[3];
    for (int kk = 0; kk < 3; ++kk) {
      float bv = -1.f; int bi = -1;
      for (int e = 0; e < 8; ++e)
        if (!used[e] && p[e] > bv) { bv = p[e]; bi = e; }
      used[bi] = 1; tv[kk] = bv; ti[kk] = bi;
    }
    float m2 = tv[0];
    float s2 = 0.f, gg[3];
    for (int kk = 0; kk < 3; ++kk) { gg[kk] = expf(tv[kk] - m2); s2 += gg[kk]; }
    for (int kk = 0; kk < 3; ++kk) { gates[kk] = gg[kk] / s2; topi[kk] = ti[kk]; }
  }
}

// F8: hh[kk] = gelu(attd @ eW1[ei].T + eb1[ei]),  grid (1024, 3)
__global__ __launch_bounds__(256) void k_hh(const float* __restrict__ attd,
                                            const float* __restrict__ eW1,
                                            const float* __restrict__ eb1,
                                            const int* __restrict__ topi,
                                            float* __restrict__ hh) {
  __shared__ float As[Dm];
  int kk = blockIdx.y;
  int ei = topi[kk];
  for (int t = threadIdx.x; t < Dm; t += 256) As[t] = attd[t];
  __syncthreads();
  int wave = threadIdx.x >> 6, lane = threadIdx.x & 63;
  int j = blockIdx.x * 4 + wave;   // 4096 outputs
  const float* Wr = eW1 + (size_t)ei * 4096 * Dm + (size_t)j * Dm;
  float acc = 0.f;
  for (int i = lane * 4; i < Dm; i += 256) {
    float4 w = *(const float4*)(Wr + i);
    float4 a = *(const float4*)(As + i);
    acc += dot4(w, a);
  }
#pragma unroll
  for (int o = 32; o > 0; o >>= 1) acc += __shfl_down(acc, o, 64);
  if (lane == 0) {
    float v = acc + eb1[(size_t)ei * 4096 + j];
    hh[(size_t)kk * 4096 + j] = 0.5f * v * (1.f + erff(v * 0.70710678118654752f));
  }
}

// F9: y[kk] = hh[kk] @ eW2[ei].T + eb2[ei]; last block: per-expert LN + gated combine
__global__ __launch_bounds__(256) void k_y_final(const float* __restrict__ hh,
                                                 const float* __restrict__ eW2,
                                                 const float* __restrict__ eb2,
                                                 const int* __restrict__ topi,
                                                 const float* __restrict__ gates,
                                                 const float* __restrict__ e_gamma,
                                                 const float* __restrict__ e_beta,
                                                 float* __restrict__ ybuf,
                                                 float* __restrict__ outp,
                                                 int* __restrict__ cnt) {
  __shared__ float As[4096];
  __shared__ float r1[256], r2[256];
  __shared__ float smu, srstd;
  __shared__ int amLast;
  int tid = threadIdx.x, wave = tid >> 6, lane = tid & 63;
  int kk = blockIdx.y;
  int ei = topi[kk];
  for (int t = tid; t < 4096; t += 256) As[t] = hh[(size_t)kk * 4096 + t];
  __syncthreads();
  int j = blockIdx.x * 4 + wave;   // 2048 outputs / 512 blocks
  const float* Wr = eW2 + (size_t)ei * Dm * 4096 + (size_t)j * 4096;
  float acc = 0.f;
  for (int i = lane * 4; i < 4096; i += 256) {
    float4 w = *(const float4*)(Wr + i);
    float4 a = *(const float4*)(As + i);
    acc += dot4(w, a);
  }
#pragma unroll
  for (int o = 32; o > 0; o >>= 1) acc += __shfl_down(acc, o, 64);
  if (lane == 0) ybuf[(size_t)kk * Dm + j] = acc + eb2[(size_t)ei * Dm + j];
  __threadfence();
  __syncthreads();
  int total = (int)(gridDim.x * gridDim.y);
  if (tid == 0) amLast = (atomicAdd(cnt, 1) == total - 1);
  __syncthreads();
  if (!amLast) return;
  __threadfence();
  // final: per-expert LayerNorm + gated combine
  float fused[8];
#pragma unroll
  for (int t = 0; t < 8; ++t) fused[t] = 0.f;
  for (int k2 = 0; k2 < 3; ++k2) {
    int e2 = topi[k2];
    float gk = gates[k2];
    const float* yr = ybuf + (size_t)k2 * Dm;
    float s = 0.f, ss = 0.f;
#pragma unroll
    for (int t = 0; t < 8; ++t) {
      float v = yr[tid + 256 * t];
      s += v; ss += v * v;
    }
    r1[tid] = s; r2[tid] = ss;
    __syncthreads();
    for (int o = 128; o > 0; o >>= 1) {
      if (tid < o) { r1[tid] += r1[tid + o]; r2[tid] += r2[tid + o]; }
      __syncthreads();
    }
    if (tid == 0) {
      float mu = r1[0] * (1.f / 2048.f);
      float var = r2[0] * (1.f / 2048.f) - mu * mu;
      smu = mu;
      srstd = rsqrtf(var + 1e-5f);
    }
    __syncthreads();
    float mu = smu, rstd = srstd;
#pragma unroll
    for (int t = 0; t < 8; ++t) {
      int d = tid + 256 * t;
      float v = (yr[d] - mu) * rstd * e_gamma[(size_t)e2 * Dm + d] + e_beta[(size_t)e2 * Dm + d];
      fused[t] += gk * v;
    }
    __syncthreads();
  }
#pragma unroll
  for (int t = 0; t < 8; ++t) outp[tid + 256 * t] = fused[t];
}

}  // namespace

extern "C" void kernel_launch(void* const* d_in, const int* in_sizes, int n_in,
                              void* d_out, int out_size, void* d_ws, size_t ws_size,
                              hipStream_t stream) {
  const float* feats   = (const float*)d_in[0];
  const float* context = (const float*)d_in[1];
  const float* mod_emb = (const float*)d_in[2];
  const float* rW1 = (const float*)d_in[3];
  const float* rb1 = (const float*)d_in[4];
  const float* rW2 = (const float*)d_in[5];
  const float* rb2 = (const float*)d_in[6];
  const float* rW3 = (const float*)d_in[7];
  const float* rb3 = (const float*)d_in[8];
  const float* W_in  = (const float*)d_in[9];
  const float* b_in  = (const float*)d_in[10];
  const float* W_out = (const float*)d_in[11];
  const float* b_out = (const float*)d_in[12];
  const float* gW1 = (const float*)d_in[13];
  const float* gb1 = (const float*)d_in[14];
  const float* gW2 = (const float*)d_in[15];
  const float* gb2 = (const float*)d_in[16];
  const float* eW1 = (const float*)d_in[17];
  const float* eb1 = (const float*)d_in[18];
  const float* eW2 = (const float*)d_in[19];
  const float* eb2 = (const float*)d_in[20];
  const float* e_gamma = (const float*)d_in[21];
  const float* e_beta  = (const float*)d_in[22];
  float* out = (float*)d_out;
  float* ws = (float*)d_ws;

  float* xbuf = ws;                  // 131072
  float* summ = xbuf + 131072;       // 16384
  float* h1   = summ + 16384;        // 16384
  float* h2   = h1 + 16384;          // 8192
  float* q0   = h2 + 8192;           // 16384
  float* qw   = q0 + 16384;          // 262144
  float* xbar = qw + 262144;         // 32768
  float* obar = xbar + 32768;        // 2048
  float* attd = obar + 2048;         // 2048
  float* gbuf = attd + 2048;         // 1024
  float* gates = gbuf + 1024;        // 8
  int*   topi  = (int*)(gates + 8);  // 8
  float* hh   = (float*)(topi + 8);  // 12288
  float* ybuf = hh + 12288;          // 6144
  int*   cnt  = (int*)(ybuf + 6144); // 2

  const int BIG = 1 << 30;

  hipLaunchKernelGGL(k_pre, dim3(512), dim3(256), 0, stream, feats, mod_emb, xbuf, summ, cnt);
  hipLaunchKernelGGL(k_big1, dim3(1024), dim3(256), 0, stream,
                     summ, context, xbuf, rW1, rb1, W_in, b_in, h1, q0);
  hipLaunchKernelGGL(k_big2, dim3(384), dim3(256), 0, stream,
                     h1, rW2, rb2, q0, W_in, h2, qw);
  hipLaunchKernelGGL(k_attn, dim3(16), dim3(256), 0, stream,
                     h2, rW3, rb3, qw, xbuf, xbar, out + 2048);
  hipLaunchKernelGGL(k_matvec, dim3(512), dim3(256), 0, stream,
                     xbar, 128, W_in + (size_t)4096 * 2048, b_in + 4096, obar);
  hipLaunchKernelGGL(k_matvec, dim3(512), dim3(256), 0, stream,
                     obar, BIG, W_out, b_out, attd);
  hipLaunchKernelGGL(k_gbuf_gate, dim3(256), dim3(256), 0, stream,
                     attd, gW1, gb1, gW2, gb2, gbuf, gates, topi, cnt);
  hipLaunchKernelGGL(k_hh, dim3(1024, 3), dim3(256), 0, stream,
                     attd, eW1, eb1, topi, hh);
  hipLaunchKernelGGL(k_y_final, dim3(512, 3), dim3(256), 0, stream,
                     hh, eW2, eb2, topi, gates, e_gamma, e_beta, ybuf, out, cnt + 1);
}

// Round 4
// 212.569 us; speedup vs baseline: 1.6711x; 1.6711x over previous
//
#include <hip/hip_runtime.h>
#include <math.h>

namespace {

constexpr int Dm = 2048;

__device__ __forceinline__ float dot4(float4 u, float4 v) {
  return u.x * v.x + u.y * v.y + u.z * v.z + u.w * v.w;
}

// top-3 expert indices from logits (softmax is monotone; strict > matches
// jax.lax.top_k tie-break: lower index first)
__device__ __forceinline__ void top3_from_logits(const float* logits, int* ti) {
  int used0 = -1, used1 = -1;
  for (int kk = 0; kk < 3; ++kk) {
    float bv = -1e30f; int bi = -1;
    for (int e = 0; e < 8; ++e) {
      if (e == used0 || e == used1) continue;
      if (logits[e] > bv) { bv = logits[e]; bi = e; }
    }
    ti[kk] = bi;
    if (kk == 0) used0 = bi; else if (kk == 1) used1 = bi;
  }
}

// F1: xbuf = feats + mod_emb (broadcast); summ = mean_s feats + mod_emb
__global__ __launch_bounds__(256) void k_pre(const float* __restrict__ feats,
                                             const float* __restrict__ mod,
                                             float* __restrict__ xbuf,
                                             float* __restrict__ summ) {
  int idx = blockIdx.x * 256 + threadIdx.x;   // 131072 total (512 blocks)
  int b = idx >> 11, i = idx & 2047;
  xbuf[idx] = feats[idx] + mod[((b >> 3) << 11) + i];
  if (blockIdx.x < 64) {
    int sidx = idx;                            // 0..16383
    int m = sidx >> 11;
    float s = 0.f;
#pragma unroll
    for (int t = 0; t < 8; ++t) s += feats[((m * 8 + t) << 11) + (sidx & 2047)];
    summ[sidx] = s * 0.125f + mod[sidx];
  }
}

// F2: blocks 0..511 -> h1 = relu([summ|ctx] @ rW1.T + rb1);  512..1023 -> q0 = x0 @ Wq.T + b
__global__ __launch_bounds__(256) void k_big1(const float* __restrict__ summ,
                                              const float* __restrict__ ctx,
                                              const float* __restrict__ xbuf,
                                              const float* __restrict__ rW1,
                                              const float* __restrict__ rb1,
                                              const float* __restrict__ W_in,
                                              const float* __restrict__ b_in,
                                              float* __restrict__ h1,
                                              float* __restrict__ q0) {
  __shared__ float As[8 * Dm];
  int tid = threadIdx.x, wave = tid >> 6, lane = tid & 63;
  if (blockIdx.x < 512) {
    for (int t = tid; t < 8 * Dm; t += 256) As[t] = summ[t];
    __syncthreads();
    int j = blockIdx.x * 4 + wave;
    const float* Wr = rW1 + (size_t)j * 4096;
    float acc[8] = {0, 0, 0, 0, 0, 0, 0, 0};
    float accC = 0.f;
    for (int i = lane * 4; i < Dm; i += 256) {
      float4 w1 = *(const float4*)(Wr + i);
      float4 w2 = *(const float4*)(Wr + 2048 + i);
      float4 c = *(const float4*)(ctx + i);
      accC += dot4(w2, c);
#pragma unroll
      for (int m = 0; m < 8; ++m) {
        float4 a = *(const float4*)(As + (m << 11) + i);
        acc[m] += dot4(w1, a);
      }
    }
#pragma unroll
    for (int o = 32; o > 0; o >>= 1) {
      accC += __shfl_down(accC, o, 64);
#pragma unroll
      for (int m = 0; m < 8; ++m) acc[m] += __shfl_down(acc[m], o, 64);
    }
    if (lane == 0) {
      float base = accC + rb1[j];
#pragma unroll
      for (int m = 0; m < 8; ++m) h1[(m << 11) + j] = fmaxf(acc[m] + base, 0.f);
    }
  } else {
    for (int t = tid; t < 8 * Dm; t += 256) {
      int m = t >> 11;
      As[t] = xbuf[(size_t)(m * 8) * Dm + (t & 2047)];   // x[m,0,:]
    }
    __syncthreads();
    int j = (blockIdx.x - 512) * 4 + wave;
    const float* Wr = W_in + (size_t)j * Dm;
    float acc[8] = {0, 0, 0, 0, 0, 0, 0, 0};
    for (int i = lane * 4; i < Dm; i += 256) {
      float4 w = *(const float4*)(Wr + i);
#pragma unroll
      for (int m = 0; m < 8; ++m) {
        float4 a = *(const float4*)(As + (m << 11) + i);
        acc[m] += dot4(w, a);
      }
    }
#pragma unroll
    for (int o = 32; o > 0; o >>= 1)
#pragma unroll
      for (int m = 0; m < 8; ++m) acc[m] += __shfl_down(acc[m], o, 64);
    if (lane == 0) {
      float b = b_in[j];
#pragma unroll
      for (int m = 0; m < 8; ++m) q0[(m << 11) + j] = acc[m] + b;
    }
  }
}

// F3: blocks 0..255 -> h2 = relu(h1 @ rW2.T + rb2); 256..383 -> qw (per-head K projection)
__global__ __launch_bounds__(256) void k_big2(const float* __restrict__ h1,
                                              const float* __restrict__ rW2,
                                              const float* __restrict__ rb2,
                                              const float* __restrict__ q0,
                                              const float* __restrict__ W_in,
                                              float* __restrict__ h2,
                                              float* __restrict__ qw) {
  __shared__ float As[8 * Dm];
  int tid = threadIdx.x, wave = tid >> 6, lane = tid & 63;
  if (blockIdx.x < 256) {
    for (int t = tid; t < 8 * Dm; t += 256) As[t] = h1[t];
    __syncthreads();
    int j = blockIdx.x * 4 + wave;     // 0..1023
    const float* Wr = rW2 + (size_t)j * Dm;
    float acc[8] = {0, 0, 0, 0, 0, 0, 0, 0};
    for (int i = lane * 4; i < Dm; i += 256) {
      float4 w = *(const float4*)(Wr + i);
#pragma unroll
      for (int m = 0; m < 8; ++m) {
        float4 a = *(const float4*)(As + (m << 11) + i);
        acc[m] += dot4(w, a);
      }
    }
#pragma unroll
    for (int o = 32; o > 0; o >>= 1)
#pragma unroll
      for (int m = 0; m < 8; ++m) acc[m] += __shfl_down(acc[m], o, 64);
    if (lane == 0) {
      float b = rb2[j];
#pragma unroll
      for (int m = 0; m < 8; ++m) h2[m * 1024 + j] = fmaxf(acc[m] + b, 0.f);
    }
  } else {
    int bb = blockIdx.x - 256;          // 0..127
    int h = bb >> 3, chunk = bb & 7;
    int i0 = chunk * 256 + tid;
    for (int t = tid; t < 1024; t += 256) {
      int m = t >> 7, d = t & 127;
      As[t] = q0[(m << 11) + h * 128 + d];
    }
    __syncthreads();
    float acc[8] = {0, 0, 0, 0, 0, 0, 0, 0};
    const float* Wb = W_in + (size_t)(Dm + h * 128) * Dm + i0;
    for (int d = 0; d < 128; ++d) {
      float w = Wb[(size_t)d * Dm];
#pragma unroll
      for (int m = 0; m < 8; ++m) acc[m] += w * As[(m << 7) + d];
    }
#pragma unroll
    for (int m = 0; m < 8; ++m) qw[(size_t)(m * 16 + h) * Dm + i0] = acc[m];
  }
}

// F4: per-head block: redundant routing head + attention weights + xbar[h]
__global__ __launch_bounds__(256) void k_attn(const float* __restrict__ h2,
                                              const float* __restrict__ rW3,
                                              const float* __restrict__ rb3,
                                              const float* __restrict__ qw,
                                              const float* __restrict__ xbuf,
                                              float* __restrict__ xbar,
                                              float* __restrict__ out_rw) {
  __shared__ float sig[8], wm[64], sv[64], att[64], mask_s[8];
  int tid = threadIdx.x, wave = tid >> 6, lane = tid & 63;
  int h = blockIdx.x;
  for (int mi = 0; mi < 2; ++mi) {
    int m = wave + mi * 4;
    float acc = 0.f;
    for (int i = lane * 4; i < 1024; i += 256) {
      float4 w = *(const float4*)(rW3 + i);
      float4 a = *(const float4*)(h2 + m * 1024 + i);
      acc += dot4(w, a);
    }
#pragma unroll
    for (int o = 32; o > 0; o >>= 1) acc += __shfl_down(acc, o, 64);
    if (lane == 0) sig[m] = 1.f / (1.f + expf(-(acc + rb3[0])));
  }
  __syncthreads();
  if (tid < 64) {
    float tot = 0.f;
#pragma unroll
    for (int m = 0; m < 8; ++m) tot += sig[m];
    int r = tid >> 3, c = tid & 7;
    wm[tid] = (sig[r] / tot) * (sig[c] / tot);
    if (h == 0 && tid < 8) out_rw[tid] = sig[tid] / tot;
  }
  __syncthreads();
  if (tid < 64) {
    float v = wm[tid];
    int rank = 0;
    for (int t = 0; t < 64; ++t) {
      float u = wm[t];
      rank += (u < v) || (u == v && t < tid);
    }
    sv[rank] = v;
  }
  __syncthreads();
  if (tid < 8) {
    double pos = 0.9 * 63.0;
    int lo = (int)pos;
    double frac = pos - (double)lo;
    float thr = (float)((double)sv[lo] + frac * ((double)sv[lo + 1] - (double)sv[lo]));
    mask_s[tid] = (wm[tid] < thr) ? -1e9f : 0.f;   // row 0 of wmat
  }
  __syncthreads();
  for (int mi = 0; mi < 2; ++mi) {
    int m = wave + mi * 4;
    const float* qr = qw + (size_t)(m * 16 + h) * Dm;
    float sc[8];
#pragma unroll
    for (int k = 0; k < 8; ++k) {
      const float* xr = xbuf + (size_t)(m * 8 + k) * Dm;
      float acc = 0.f;
      for (int i = lane * 4; i < Dm; i += 256) {
        float4 qv = *(const float4*)(qr + i);
        float4 xv = *(const float4*)(xr + i);
        acc += dot4(qv, xv);
      }
#pragma unroll
      for (int o = 32; o > 0; o >>= 1) acc += __shfl_xor(acc, o, 64);
      sc[k] = acc * 0.08838834764831845f + mask_s[k];
    }
    float mx = sc[0];
#pragma unroll
    for (int k = 1; k < 8; ++k) mx = fmaxf(mx, sc[k]);
    float se = 0.f;
#pragma unroll
    for (int k = 0; k < 8; ++k) { sc[k] = expf(sc[k] - mx); se += sc[k]; }
    float inv = 1.f / se;
    if (lane == 0) {
#pragma unroll
      for (int k = 0; k < 8; ++k) att[m * 8 + k] = sc[k] * inv;
    }
  }
  __syncthreads();
  for (int i = tid; i < Dm; i += 256) {
    float acc = 0.f;
#pragma unroll
    for (int b = 0; b < 64; ++b) acc += att[b] * xbuf[(size_t)b * Dm + i];
    xbar[(size_t)h * Dm + i] = acc * 0.125f;
  }
}

// generic 4-row matvec: out[j] = act(dot(Arow(j/G), W[j]) + b1[j]); ACT 0 none, 1 relu
template <int ACT>
__global__ __launch_bounds__(256) void k_matvec(const float* __restrict__ A, int G,
                                                const float* __restrict__ W,
                                                const float* __restrict__ b1,
                                                float* __restrict__ out) {
  __shared__ float As[Dm];
  int j0 = blockIdx.x * 4;
  const float* Arow = A + (size_t)(j0 / G) * Dm;
  for (int t = threadIdx.x; t < Dm; t += 256) As[t] = Arow[t];
  __syncthreads();
  int wave = threadIdx.x >> 6, lane = threadIdx.x & 63;
  int j = j0 + wave;
  const float* Wr = W + (size_t)j * Dm;
  float acc = 0.f;
  for (int i = lane * 4; i < Dm; i += 256) {
    float4 w = *(const float4*)(Wr + i);
    float4 a = *(const float4*)(As + i);
    acc += dot4(w, a);
  }
#pragma unroll
  for (int o = 32; o > 0; o >>= 1) acc += __shfl_down(acc, o, 64);
  if (lane == 0) {
    float v = acc + b1[j];
    if (ACT == 1) v = fmaxf(v, 0.f);
    out[j] = v;
  }
}

// redundant gate-logit computation (256 threads) -> logits[8] in shared
__device__ __forceinline__ void gate_logits(const float* __restrict__ gbuf,
                                            const float* __restrict__ gW2,
                                            const float* __restrict__ gb2,
                                            float* logits /*shared[8]*/) {
  int tid = threadIdx.x, wave = tid >> 6, lane = tid & 63;
  for (int e = wave; e < 8; e += 4) {
    float a2 = 0.f;
    for (int i = lane * 4; i < 1024; i += 256) {
      float4 w = *(const float4*)(gW2 + e * 1024 + i);
      float4 g = *(const float4*)(gbuf + i);
      a2 += dot4(w, g);
    }
#pragma unroll
    for (int o = 32; o > 0; o >>= 1) a2 += __shfl_down(a2, o, 64);
    if (lane == 0) logits[e] = a2 + gb2[e];
  }
  __syncthreads();
}

// F8: hh[kk] = gelu(attd @ eW1[ei].T + eb1[ei]); ei from redundant gate top-3
__global__ __launch_bounds__(256) void k_hh(const float* __restrict__ attd,
                                            const float* __restrict__ gbuf,
                                            const float* __restrict__ gW2,
                                            const float* __restrict__ gb2,
                                            const float* __restrict__ eW1,
                                            const float* __restrict__ eb1,
                                            float* __restrict__ hh) {
  __shared__ float As[Dm];
  __shared__ float logits[8];
  __shared__ int s_ei;
  int tid = threadIdx.x, wave = tid >> 6, lane = tid & 63;
  int kk = blockIdx.y;
  gate_logits(gbuf, gW2, gb2, logits);
  if (tid == 0) {
    int ti[3];
    top3_from_logits(logits, ti);
    s_ei = ti[kk];
  }
  for (int t = tid; t < Dm; t += 256) As[t] = attd[t];
  __syncthreads();
  int ei = s_ei;
  int j = blockIdx.x * 4 + wave;   // 4096 outputs
  const float* Wr = eW1 + (size_t)ei * 4096 * Dm + (size_t)j * Dm;
  float acc = 0.f;
  for (int i = lane * 4; i < Dm; i += 256) {
    float4 w = *(const float4*)(Wr + i);
    float4 a = *(const float4*)(As + i);
    acc += dot4(w, a);
  }
#pragma unroll
  for (int o = 32; o > 0; o >>= 1) acc += __shfl_down(acc, o, 64);
  if (lane == 0) {
    float v = acc + eb1[(size_t)ei * 4096 + j];
    hh[(size_t)kk * 4096 + j] = 0.5f * v * (1.f + erff(v * 0.70710678118654752f));
  }
}

// F9: y[kk] = hh[kk] @ eW2[ei].T + eb2[ei]; ei from redundant gate top-3
__global__ __launch_bounds__(256) void k_y(const float* __restrict__ hh,
                                           const float* __restrict__ gbuf,
                                           const float* __restrict__ gW2,
                                           const float* __restrict__ gb2,
                                           const float* __restrict__ eW2,
                                           const float* __restrict__ eb2,
                                           float* __restrict__ ybuf) {
  __shared__ float As[4096];
  __shared__ float logits[8];
  __shared__ int s_ei;
  int tid = threadIdx.x, wave = tid >> 6, lane = tid & 63;
  int kk = blockIdx.y;
  gate_logits(gbuf, gW2, gb2, logits);
  if (tid == 0) {
    int ti[3];
    top3_from_logits(logits, ti);
    s_ei = ti[kk];
  }
  for (int t = tid; t < 4096; t += 256) As[t] = hh[(size_t)kk * 4096 + t];
  __syncthreads();
  int ei = s_ei;
  int j = blockIdx.x * 4 + wave;   // 2048 outputs / 512 blocks
  const float* Wr = eW2 + (size_t)ei * Dm * 4096 + (size_t)j * 4096;
  float acc = 0.f;
  for (int i = lane * 4; i < 4096; i += 256) {
    float4 w = *(const float4*)(Wr + i);
    float4 a = *(const float4*)(As + i);
    acc += dot4(w, a);
  }
#pragma unroll
  for (int o = 32; o > 0; o >>= 1) acc += __shfl_down(acc, o, 64);
  if (lane == 0) ybuf[(size_t)kk * Dm + j] = acc + eb2[(size_t)ei * Dm + j];
}

// F10: one block: gate (probs + top3 + renorm) + per-expert LN + gated combine
__global__ __launch_bounds__(256) void k_final(const float* __restrict__ ybuf,
                                               const float* __restrict__ gbuf,
                                               const float* __restrict__ gW2,
                                               const float* __restrict__ gb2,
                                               const float* __restrict__ e_gamma,
                                               const float* __restrict__ e_beta,
                                               float* __restrict__ outp) {
  __shared__ float logits[8];
  __shared__ float r1[256], r2[256];
  __shared__ float smu, srstd;
  __shared__ float s_gates[3];
  __shared__ int s_topi[3];
  int tid = threadIdx.x;
  gate_logits(gbuf, gW2, gb2, logits);
  if (tid == 0) {
    float mx = logits[0];
    for (int e = 1; e < 8; ++e) mx = fmaxf(mx, logits[e]);
    float p[8], se = 0.f;
    for (int e = 0; e < 8; ++e) { p[e] = expf(logits[e] - mx); se += p[e]; }
    for (int e = 0; e < 8; ++e) p[e] /= se;
    int ti[3];
    top3_from_logits(logits, ti);
    float tv[3];
    for (int kk = 0; kk < 3; ++kk) tv[kk] = p[ti[kk]];
    float m2 = tv[0];
    float s2 = 0.f, gg[3];
    for (int kk = 0; kk < 3; ++kk) { gg[kk] = expf(tv[kk] - m2); s2 += gg[kk]; }
    for (int kk = 0; kk < 3; ++kk) { s_gates[kk] = gg[kk] / s2; s_topi[kk] = ti[kk]; }
  }
  __syncthreads();
  float fused[8];
#pragma unroll
  for (int t = 0; t < 8; ++t) fused[t] = 0.f;
  for (int k2 = 0; k2 < 3; ++k2) {
    int e2 = s_topi[k2];
    float gk = s_gates[k2];
    const float* yr = ybuf + (size_t)k2 * Dm;
    float s = 0.f, ss = 0.f;
#pragma unroll
    for (int t = 0; t < 8; ++t) {
      float v = yr[tid + 256 * t];
      s += v; ss += v * v;
    }
    r1[tid] = s; r2[tid] = ss;
    __syncthreads();
    for (int o = 128; o > 0; o >>= 1) {
      if (tid < o) { r1[tid] += r1[tid + o]; r2[tid] += r2[tid + o]; }
      __syncthreads();
    }
    if (tid == 0) {
      float mu = r1[0] * (1.f / 2048.f);
      float var = r2[0] * (1.f / 2048.f) - mu * mu;
      smu = mu;
      srstd = rsqrtf(var + 1e-5f);
    }
    __syncthreads();
    float mu = smu, rstd = srstd;
#pragma unroll
    for (int t = 0; t < 8; ++t) {
      int d = tid + 256 * t;
      float v = (yr[d] - mu) * rstd * e_gamma[(size_t)e2 * Dm + d] + e_beta[(size_t)e2 * Dm + d];
      fused[t] += gk * v;
    }
    __syncthreads();
  }
#pragma unroll
  for (int t = 0; t < 8; ++t) outp[tid + 256 * t] = fused[t];
}

}  // namespace

extern "C" void kernel_launch(void* const* d_in, const int* in_sizes, int n_in,
                              void* d_out, int out_size, void* d_ws, size_t ws_size,
                              hipStream_t stream) {
  const float* feats   = (const float*)d_in[0];
  const float* context = (const float*)d_in[1];
  const float* mod_emb = (const float*)d_in[2];
  const float* rW1 = (const float*)d_in[3];
  const float* rb1 = (const float*)d_in[4];
  const float* rW2 = (const float*)d_in[5];
  const float* rb2 = (const float*)d_in[6];
  const float* rW3 = (const float*)d_in[7];
  const float* rb3 = (const float*)d_in[8];
  const float* W_in  = (const float*)d_in[9];
  const float* b_in  = (const float*)d_in[10];
  const float* W_out = (const float*)d_in[11];
  const float* b_out = (const float*)d_in[12];
  const float* gW1 = (const float*)d_in[13];
  const float* gb1 = (const float*)d_in[14];
  const float* gW2 = (const float*)d_in[15];
  const float* gb2 = (const float*)d_in[16];
  const float* eW1 = (const float*)d_in[17];
  const float* eb1 = (const float*)d_in[18];
  const float* eW2 = (const float*)d_in[19];
  const float* eb2 = (const float*)d_in[20];
  const float* e_gamma = (const float*)d_in[21];
  const float* e_beta  = (const float*)d_in[22];
  float* out = (float*)d_out;
  float* ws = (float*)d_ws;

  float* xbuf = ws;                  // 131072
  float* summ = xbuf + 131072;       // 16384
  float* h1   = summ + 16384;        // 16384
  float* h2   = h1 + 16384;          // 8192
  float* q0   = h2 + 8192;           // 16384
  float* qw   = q0 + 16384;          // 262144
  float* xbar = qw + 262144;         // 32768
  float* obar = xbar + 32768;        // 2048
  float* attd = obar + 2048;         // 2048
  float* gbuf = attd + 2048;         // 1024
  float* hh   = gbuf + 1024;         // 12288
  float* ybuf = hh + 12288;          // 6144

  const int BIG = 1 << 30;

  hipLaunchKernelGGL(k_pre, dim3(512), dim3(256), 0, stream, feats, mod_emb, xbuf, summ);
  hipLaunchKernelGGL(k_big1, dim3(1024), dim3(256), 0, stream,
                     summ, context, xbuf, rW1, rb1, W_in, b_in, h1, q0);
  hipLaunchKernelGGL(k_big2, dim3(384), dim3(256), 0, stream,
                     h1, rW2, rb2, q0, W_in, h2, qw);
  hipLaunchKernelGGL(k_attn, dim3(16), dim3(256), 0, stream,
                     h2, rW3, rb3, qw, xbuf, xbar, out + 2048);
  hipLaunchKernelGGL(k_matvec<0>, dim3(512), dim3(256), 0, stream,
                     xbar, 128, W_in + (size_t)4096 * 2048, b_in + 4096, obar);
  hipLaunchKernelGGL(k_matvec<0>, dim3(512), dim3(256), 0, stream,
                     obar, BIG, W_out, b_out, attd);
  hipLaunchKernelGGL(k_matvec<1>, dim3(256), dim3(256), 0, stream,
                     attd, BIG, gW1, gb1, gbuf);
  hipLaunchKernelGGL(k_hh, dim3(1024, 3), dim3(256), 0, stream,
                     attd, gbuf, gW2, gb2, eW1, eb1, hh);
  hipLaunchKernelGGL(k_y, dim3(512, 3), dim3(256), 0, stream,
                     hh, gbuf, gW2, gb2, eW2, eb2, ybuf);
  hipLaunchKernelGGL(k_final, dim3(1), dim3(256), 0, stream,
                     ybuf, gbuf, gW2, gb2, e_gamma, e_beta, out);
}

// Round 5
// 150.663 us; speedup vs baseline: 2.3577x; 1.4109x over previous
//
#include <hip/hip_runtime.h>
#include <math.h>

namespace {

constexpr int Dm = 2048;

__device__ __forceinline__ float dot4(float4 u, float4 v) {
  return u.x * v.x + u.y * v.y + u.z * v.z + u.w * v.w;
}

// F1: xbuf = feats + mod_emb (broadcast); summ = mean_s feats + mod_emb
__global__ __launch_bounds__(256) void k_pre(const float* __restrict__ feats,
                                             const float* __restrict__ mod,
                                             float* __restrict__ xbuf,
                                             float* __restrict__ summ) {
  int idx = blockIdx.x * 256 + threadIdx.x;   // 131072 total (512 blocks)
  int b = idx >> 11, i = idx & 2047;
  xbuf[idx] = feats[idx] + mod[((b >> 3) << 11) + i];
  if (blockIdx.x < 64) {
    int sidx = idx;                            // 0..16383
    int m = sidx >> 11;
    float s = 0.f;
#pragma unroll
    for (int t = 0; t < 8; ++t) s += feats[((m * 8 + t) << 11) + (sidx & 2047)];
    summ[sidx] = s * 0.125f + mod[sidx];
  }
}

// F2: blocks 0..511 -> h1 = relu([summ|ctx] @ rW1.T + rb1);  512..1023 -> q0 = x0 @ Wq.T + b
__global__ __launch_bounds__(256) void k_big1(const float* __restrict__ summ,
                                              const float* __restrict__ ctx,
                                              const float* __restrict__ xbuf,
                                              const float* __restrict__ rW1,
                                              const float* __restrict__ rb1,
                                              const float* __restrict__ W_in,
                                              const float* __restrict__ b_in,
                                              float* __restrict__ h1,
                                              float* __restrict__ q0) {
  __shared__ float As[8 * Dm];
  int tid = threadIdx.x, wave = tid >> 6, lane = tid & 63;
  if (blockIdx.x < 512) {
    for (int t = tid; t < 8 * Dm; t += 256) As[t] = summ[t];
    __syncthreads();
    int j = blockIdx.x * 4 + wave;
    const float* Wr = rW1 + (size_t)j * 4096;
    float acc[8] = {0, 0, 0, 0, 0, 0, 0, 0};
    float accC = 0.f;
    for (int i = lane * 4; i < Dm; i += 256) {
      float4 w1 = *(const float4*)(Wr + i);
      float4 w2 = *(const float4*)(Wr + 2048 + i);
      float4 c = *(const float4*)(ctx + i);
      accC += dot4(w2, c);
#pragma unroll
      for (int m = 0; m < 8; ++m) {
        float4 a = *(const float4*)(As + (m << 11) + i);
        acc[m] += dot4(w1, a);
      }
    }
#pragma unroll
    for (int o = 32; o > 0; o >>= 1) {
      accC += __shfl_down(accC, o, 64);
#pragma unroll
      for (int m = 0; m < 8; ++m) acc[m] += __shfl_down(acc[m], o, 64);
    }
    if (lane == 0) {
      float base = accC + rb1[j];
#pragma unroll
      for (int m = 0; m < 8; ++m) h1[(m << 11) + j] = fmaxf(acc[m] + base, 0.f);
    }
  } else {
    for (int t = tid; t < 8 * Dm; t += 256) {
      int m = t >> 11;
      As[t] = xbuf[(size_t)(m * 8) * Dm + (t & 2047)];   // x[m,0,:]
    }
    __syncthreads();
    int j = (blockIdx.x - 512) * 4 + wave;
    const float* Wr = W_in + (size_t)j * Dm;
    float acc[8] = {0, 0, 0, 0, 0, 0, 0, 0};
    for (int i = lane * 4; i < Dm; i += 256) {
      float4 w = *(const float4*)(Wr + i);
#pragma unroll
      for (int m = 0; m < 8; ++m) {
        float4 a = *(const float4*)(As + (m << 11) + i);
        acc[m] += dot4(w, a);
      }
    }
#pragma unroll
    for (int o = 32; o > 0; o >>= 1)
#pragma unroll
      for (int m = 0; m < 8; ++m) acc[m] += __shfl_down(acc[m], o, 64);
    if (lane == 0) {
      float b = b_in[j];
#pragma unroll
      for (int m = 0; m < 8; ++m) q0[(m << 11) + j] = acc[m] + b;
    }
  }
}

// F3: blocks 0..255 -> h2 = relu(h1 @ rW2.T + rb2); 256..383 -> qw (per-head K projection)
__global__ __launch_bounds__(256) void k_big2(const float* __restrict__ h1,
                                              const float* __restrict__ rW2,
                                              const float* __restrict__ rb2,
                                              const float* __restrict__ q0,
                                              const float* __restrict__ W_in,
                                              float* __restrict__ h2,
                                              float* __restrict__ qw) {
  __shared__ float As[8 * Dm];
  int tid = threadIdx.x, wave = tid >> 6, lane = tid & 63;
  if (blockIdx.x < 256) {
    for (int t = tid; t < 8 * Dm; t += 256) As[t] = h1[t];
    __syncthreads();
    int j = blockIdx.x * 4 + wave;     // 0..1023
    const float* Wr = rW2 + (size_t)j * Dm;
    float acc[8] = {0, 0, 0, 0, 0, 0, 0, 0};
    for (int i = lane * 4; i < Dm; i += 256) {
      float4 w = *(const float4*)(Wr + i);
#pragma unroll
      for (int m = 0; m < 8; ++m) {
        float4 a = *(const float4*)(As + (m << 11) + i);
        acc[m] += dot4(w, a);
      }
    }
#pragma unroll
    for (int o = 32; o > 0; o >>= 1)
#pragma unroll
      for (int m = 0; m < 8; ++m) acc[m] += __shfl_down(acc[m], o, 64);
    if (lane == 0) {
      float b = rb2[j];
#pragma unroll
      for (int m = 0; m < 8; ++m) h2[m * 1024 + j] = fmaxf(acc[m] + b, 0.f);
    }
  } else {
    int bb = blockIdx.x - 256;          // 0..127
    int h = bb >> 3, chunk = bb & 7;
    int i0 = chunk * 256 + tid;
    for (int t = tid; t < 1024; t += 256) {
      int m = t >> 7, d = t & 127;
      As[t] = q0[(m << 11) + h * 128 + d];
    }
    __syncthreads();
    float acc[8] = {0, 0, 0, 0, 0, 0, 0, 0};
    const float* Wb = W_in + (size_t)(Dm + h * 128) * Dm + i0;
    for (int d = 0; d < 128; ++d) {
      float w = Wb[(size_t)d * Dm];
#pragma unroll
      for (int m = 0; m < 8; ++m) acc[m] += w * As[(m << 7) + d];
    }
#pragma unroll
    for (int m = 0; m < 8; ++m) qw[(size_t)(m * 16 + h) * Dm + i0] = acc[m];
  }
}

// F4: routing head (1 block): rw -> out, mask row 0 -> ws
__global__ __launch_bounds__(256) void k_route(const float* __restrict__ h2,
                                               const float* __restrict__ rW3,
                                               const float* __restrict__ rb3,
                                               float* __restrict__ maskv,
                                               float* __restrict__ out_rw) {
  __shared__ float sig[8], wm[64], sv[64];
  int tid = threadIdx.x, wave = tid >> 6, lane = tid & 63;
  for (int mi = 0; mi < 2; ++mi) {
    int m = wave + mi * 4;
    float acc = 0.f;
    for (int i = lane * 4; i < 1024; i += 256) {
      float4 w = *(const float4*)(rW3 + i);
      float4 a = *(const float4*)(h2 + m * 1024 + i);
      acc += dot4(w, a);
    }
#pragma unroll
    for (int o = 32; o > 0; o >>= 1) acc += __shfl_down(acc, o, 64);
    if (lane == 0) sig[m] = 1.f / (1.f + expf(-(acc + rb3[0])));
  }
  __syncthreads();
  if (tid < 64) {
    float tot = 0.f;
#pragma unroll
    for (int m = 0; m < 8; ++m) tot += sig[m];
    int r = tid >> 3, c = tid & 7;
    wm[tid] = (sig[r] / tot) * (sig[c] / tot);
    if (tid < 8) out_rw[tid] = sig[tid] / tot;
  }
  __syncthreads();
  if (tid < 64) {
    float v = wm[tid];
    int rank = 0;
    for (int t = 0; t < 64; ++t) {
      float u = wm[t];
      rank += (u < v) || (u == v && t < tid);
    }
    sv[rank] = v;
  }
  __syncthreads();
  if (tid < 8) {
    double pos = 0.9 * 63.0;
    int lo = (int)pos;
    double frac = pos - (double)lo;
    float thr = (float)((double)sv[lo] + frac * ((double)sv[lo + 1] - (double)sv[lo]));
    maskv[tid] = (wm[tid] < thr) ? -1e9f : 0.f;
  }
}

// F5: attention weights; 32 blocks x 4 waves, wave = one (m,h)
__global__ __launch_bounds__(256) void k_attnw(const float* __restrict__ qw,
                                               const float* __restrict__ xbuf,
                                               const float* __restrict__ maskv,
                                               float* __restrict__ attw) {
  __shared__ float mask_s[8];
  int tid = threadIdx.x, wave = tid >> 6, lane = tid & 63;
  if (tid < 8) mask_s[tid] = maskv[tid];
  __syncthreads();
  int mh = blockIdx.x * 4 + wave;   // 0..127
  int m = mh >> 4;
  const float* qr = qw + (size_t)mh * Dm;
  float sc[8];
#pragma unroll
  for (int k = 0; k < 8; ++k) {
    const float* xr = xbuf + (size_t)(m * 8 + k) * Dm;
    float acc = 0.f;
    for (int i = lane * 4; i < Dm; i += 256) {
      float4 qv = *(const float4*)(qr + i);
      float4 xv = *(const float4*)(xr + i);
      acc += dot4(qv, xv);
    }
#pragma unroll
    for (int o = 32; o > 0; o >>= 1) acc += __shfl_xor(acc, o, 64);
    sc[k] = acc * 0.08838834764831845f + mask_s[k];
  }
  float mx = sc[0];
#pragma unroll
  for (int k = 1; k < 8; ++k) mx = fmaxf(mx, sc[k]);
  float se = 0.f;
#pragma unroll
  for (int k = 0; k < 8; ++k) { sc[k] = expf(sc[k] - mx); se += sc[k]; }
  float inv = 1.f / se;
  if (lane == 0) {
#pragma unroll
    for (int k = 0; k < 8; ++k) attw[mh * 8 + k] = sc[k] * inv;
  }
}

// F6: xbar[h][i] = (1/8) sum_m sum_k attw[m,h,k] * x[m*8+k][i]
__global__ __launch_bounds__(256) void k_xbar(const float* __restrict__ attw,
                                              const float* __restrict__ xbuf,
                                              float* __restrict__ xbar) {
  __shared__ float aw[64];
  int h = blockIdx.y;
  int i = blockIdx.x * 256 + threadIdx.x;
  if (threadIdx.x < 64) {
    int m = threadIdx.x >> 3, k = threadIdx.x & 7;
    aw[threadIdx.x] = attw[(m * 16 + h) * 8 + k];
  }
  __syncthreads();
  float acc = 0.f;
#pragma unroll
  for (int b = 0; b < 64; ++b) acc += aw[b] * xbuf[(size_t)b * Dm + i];
  xbar[(size_t)h * Dm + i] = acc * 0.125f;
}

// 8-rows-per-block matvec (2 rows/wave): out[j] = act(dot(Arow(j/G), W[j]) + b1[j])
template <int ACT>
__global__ __launch_bounds__(256) void k_matvec8(const float* __restrict__ A, int G,
                                                 const float* __restrict__ W,
                                                 const float* __restrict__ b1,
                                                 float* __restrict__ out) {
  __shared__ float As[Dm];
  int j0 = blockIdx.x * 8;
  const float* Arow = A + (size_t)(j0 / G) * Dm;
  for (int t = threadIdx.x; t < Dm; t += 256) As[t] = Arow[t];
  __syncthreads();
  int wave = threadIdx.x >> 6, lane = threadIdx.x & 63;
  int j = j0 + wave * 2;
  const float* W0 = W + (size_t)j * Dm;
  const float* W1 = W0 + Dm;
  float acc0 = 0.f, acc1 = 0.f;
  for (int i = lane * 4; i < Dm; i += 256) {
    float4 a = *(const float4*)(As + i);
    float4 w0 = *(const float4*)(W0 + i);
    float4 w1 = *(const float4*)(W1 + i);
    acc0 += dot4(w0, a);
    acc1 += dot4(w1, a);
  }
#pragma unroll
  for (int o = 32; o > 0; o >>= 1) {
    acc0 += __shfl_down(acc0, o, 64);
    acc1 += __shfl_down(acc1, o, 64);
  }
  if (lane == 0) {
    float v0 = acc0 + b1[j], v1 = acc1 + b1[j + 1];
    if (ACT == 1) { v0 = fmaxf(v0, 0.f); v1 = fmaxf(v1, 0.f); }
    out[j] = v0;
    out[j + 1] = v1;
  }
}

// F10: gate: logits -> softmax -> top3(stable) -> gates/topi in ws
__global__ __launch_bounds__(512) void k_gate(const float* __restrict__ g,
                                              const float* __restrict__ gW2,
                                              const float* __restrict__ gb2,
                                              float* __restrict__ gates,
                                              int* __restrict__ topi) {
  __shared__ float logits[8];
  int wave = threadIdx.x >> 6, lane = threadIdx.x & 63;   // 512 threads
  float acc = 0.f;
  for (int i = lane * 4; i < 1024; i += 256) {
    float4 w = *(const float4*)(gW2 + wave * 1024 + i);
    float4 a = *(const float4*)(g + i);
    acc += dot4(w, a);
  }
#pragma unroll
  for (int o = 32; o > 0; o >>= 1) acc += __shfl_down(acc, o, 64);
  if (lane == 0) logits[wave] = acc + gb2[wave];
  __syncthreads();
  if (threadIdx.x == 0) {
    float mx = logits[0];
    for (int e = 1; e < 8; ++e) mx = fmaxf(mx, logits[e]);
    float p[8], se = 0.f;
    for (int e = 0; e < 8; ++e) { p[e] = expf(logits[e] - mx); se += p[e]; }
    for (int e = 0; e < 8; ++e) p[e] /= se;
    int used[8] = {0, 0, 0, 0, 0, 0, 0, 0};
    float tv[3]; int ti[3];
    for (int kk = 0; kk < 3; ++kk) {
      float bv = -1.f; int bi = -1;
      for (int e = 0; e < 8; ++e)
        if (!used[e] && p[e] > bv) { bv = p[e]; bi = e; }
      used[bi] = 1; tv[kk] = bv; ti[kk] = bi;
    }
    float m2 = tv[0];
    float s2 = 0.f, gg[3];
    for (int kk = 0; kk < 3; ++kk) { gg[kk] = expf(tv[kk] - m2); s2 += gg[kk]; }
    for (int kk = 0; kk < 3; ++kk) { gates[kk] = gg[kk] / s2; topi[kk] = ti[kk]; }
  }
}

// expert matvec, 8 rows/block (2/wave). ACT: 0 none, 2 gelu(exact)
template <int IN, int ACT>
__global__ __launch_bounds__(256) void k_expert8(const float* __restrict__ A,
                                                 int a_stride_kk,
                                                 const float* __restrict__ Wbase,
                                                 size_t wstride,
                                                 const float* __restrict__ bbase,
                                                 int bstride,
                                                 const int* __restrict__ topi,
                                                 float* __restrict__ out, int OUT) {
  __shared__ float As[IN];
  int kk = blockIdx.y;
  int ei = topi[kk];
  const float* Arow = A + (size_t)kk * a_stride_kk;
  for (int t = threadIdx.x; t < IN; t += 256) As[t] = Arow[t];
  __syncthreads();
  int wave = threadIdx.x >> 6, lane = threadIdx.x & 63;
  int j = blockIdx.x * 8 + wave * 2;
  const float* W0 = Wbase + (size_t)ei * wstride + (size_t)j * IN;
  const float* W1 = W0 + IN;
  float acc0 = 0.f, acc1 = 0.f;
  for (int i = lane * 4; i < IN; i += 256) {
    float4 a = *(const float4*)(As + i);
    float4 w0 = *(const float4*)(W0 + i);
    float4 w1 = *(const float4*)(W1 + i);
    acc0 += dot4(w0, a);
    acc1 += dot4(w1, a);
  }
#pragma unroll
  for (int o = 32; o > 0; o >>= 1) {
    acc0 += __shfl_down(acc0, o, 64);
    acc1 += __shfl_down(acc1, o, 64);
  }
  if (lane == 0) {
    const float* bb = bbase + (size_t)ei * bstride;
    float v0 = acc0 + bb[j], v1 = acc1 + bb[j + 1];
    if (ACT == 2) {
      v0 = 0.5f * v0 * (1.f + erff(v0 * 0.70710678118654752f));
      v1 = 0.5f * v1 * (1.f + erff(v1 * 0.70710678118654752f));
    }
    out[(size_t)kk * OUT + j] = v0;
    out[(size_t)kk * OUT + j + 1] = v1;
  }
}

// F13: per-expert LayerNorm + gated combine -> fused[0:2048]
__global__ __launch_bounds__(256) void k_final(const float* __restrict__ y,
                                               const float* __restrict__ gates,
                                               const int* __restrict__ topi,
                                               const float* __restrict__ e_gamma,
                                               const float* __restrict__ e_beta,
                                               float* __restrict__ outp) {
  __shared__ float r1[256], r2[256];
  __shared__ float smu, srstd;
  int tid = threadIdx.x;
  float fused[8];
#pragma unroll
  for (int t = 0; t < 8; ++t) fused[t] = 0.f;
  for (int kk = 0; kk < 3; ++kk) {
    int ei = topi[kk];
    float gk = gates[kk];
    const float* yr = y + (size_t)kk * Dm;
    float s = 0.f, ss = 0.f;
#pragma unroll
    for (int t = 0; t < 8; ++t) {
      float v = yr[tid + 256 * t];
      s += v; ss += v * v;
    }
    r1[tid] = s; r2[tid] = ss;
    __syncthreads();
    for (int o = 128; o > 0; o >>= 1) {
      if (tid < o) { r1[tid] += r1[tid + o]; r2[tid] += r2[tid + o]; }
      __syncthreads();
    }
    if (tid == 0) {
      float mu = r1[0] * (1.f / 2048.f);
      float var = r2[0] * (1.f / 2048.f) - mu * mu;
      smu = mu;
      srstd = rsqrtf(var + 1e-5f);
    }
    __syncthreads();
    float mu = smu, rstd = srstd;
#pragma unroll
    for (int t = 0; t < 8; ++t) {
      int d = tid + 256 * t;
      float v = (yr[d] - mu) * rstd * e_gamma[(size_t)ei * Dm + d] + e_beta[(size_t)ei * Dm + d];
      fused[t] += gk * v;
    }
    __syncthreads();
  }
#pragma unroll
  for (int t = 0; t < 8; ++t) outp[tid + 256 * t] = fused[t];
}

}  // namespace

extern "C" void kernel_launch(void* const* d_in, const int* in_sizes, int n_in,
                              void* d_out, int out_size, void* d_ws, size_t ws_size,
                              hipStream_t stream) {
  const float* feats   = (const float*)d_in[0];
  const float* context = (const float*)d_in[1];
  const float* mod_emb = (const float*)d_in[2];
  const float* rW1 = (const float*)d_in[3];
  const float* rb1 = (const float*)d_in[4];
  const float* rW2 = (const float*)d_in[5];
  const float* rb2 = (const float*)d_in[6];
  const float* rW3 = (const float*)d_in[7];
  const float* rb3 = (const float*)d_in[8];
  const float* W_in  = (const float*)d_in[9];
  const float* b_in  = (const float*)d_in[10];
  const float* W_out = (const float*)d_in[11];
  const float* b_out = (const float*)d_in[12];
  const float* gW1 = (const float*)d_in[13];
  const float* gb1 = (const float*)d_in[14];
  const float* gW2 = (const float*)d_in[15];
  const float* gb2 = (const float*)d_in[16];
  const float* eW1 = (const float*)d_in[17];
  const float* eb1 = (const float*)d_in[18];
  const float* eW2 = (const float*)d_in[19];
  const float* eb2 = (const float*)d_in[20];
  const float* e_gamma = (const float*)d_in[21];
  const float* e_beta  = (const float*)d_in[22];
  float* out = (float*)d_out;
  float* ws = (float*)d_ws;

  float* xbuf  = ws;                 // 131072
  float* summ  = xbuf + 131072;      // 16384
  float* h1    = summ + 16384;       // 16384
  float* h2    = h1 + 16384;         // 8192
  float* q0    = h2 + 8192;          // 16384
  float* qw    = q0 + 16384;         // 262144
  float* maskv = qw + 262144;        // 8
  float* att   = maskv + 8;          // 1024
  float* xbar  = att + 1024;         // 32768
  float* obar  = xbar + 32768;       // 2048
  float* attd  = obar + 2048;        // 2048
  float* gbuf  = attd + 2048;        // 1024
  float* gates = gbuf + 1024;        // 8
  int*   topi  = (int*)(gates + 8);  // 8
  float* hh    = (float*)(topi + 8); // 12288
  float* ybuf  = hh + 12288;         // 6144

  const int BIG = 1 << 30;

  hipLaunchKernelGGL(k_pre, dim3(512), dim3(256), 0, stream, feats, mod_emb, xbuf, summ);
  hipLaunchKernelGGL(k_big1, dim3(1024), dim3(256), 0, stream,
                     summ, context, xbuf, rW1, rb1, W_in, b_in, h1, q0);
  hipLaunchKernelGGL(k_big2, dim3(384), dim3(256), 0, stream,
                     h1, rW2, rb2, q0, W_in, h2, qw);
  hipLaunchKernelGGL(k_route, dim3(1), dim3(256), 0, stream,
                     h2, rW3, rb3, maskv, out + 2048);
  hipLaunchKernelGGL(k_attnw, dim3(32), dim3(256), 0, stream, qw, xbuf, maskv, att);
  hipLaunchKernelGGL(k_xbar, dim3(8, 16), dim3(256), 0, stream, att, xbuf, xbar);
  hipLaunchKernelGGL(k_matvec8<0>, dim3(256), dim3(256), 0, stream,
                     xbar, 128, W_in + (size_t)4096 * 2048, b_in + 4096, obar);
  hipLaunchKernelGGL(k_matvec8<0>, dim3(256), dim3(256), 0, stream,
                     obar, BIG, W_out, b_out, attd);
  hipLaunchKernelGGL(k_matvec8<1>, dim3(128), dim3(256), 0, stream,
                     attd, BIG, gW1, gb1, gbuf);
  hipLaunchKernelGGL(k_gate, dim3(1), dim3(512), 0, stream, gbuf, gW2, gb2, gates, topi);
  hipLaunchKernelGGL((k_expert8<2048, 2>), dim3(512, 3), dim3(256), 0, stream,
                     attd, 0, eW1, (size_t)4096 * 2048, eb1, 4096, topi, hh, 4096);
  hipLaunchKernelGGL((k_expert8<4096, 0>), dim3(256, 3), dim3(256), 0, stream,
                     hh, 4096, eW2, (size_t)2048 * 4096, eb2, 2048, topi, ybuf, 2048);
  hipLaunchKernelGGL(k_final, dim3(1), dim3(256), 0, stream,
                     ybuf, gates, topi, e_gamma, e_beta, out);
}